// Round 5
// baseline (262.482 us; speedup 1.0000x reference)
//
#include <hip/hip_runtime.h>
#include <hip/hip_bf16.h>
#include <math.h>

typedef __bf16 bf16;
typedef __attribute__((ext_vector_type(8))) __bf16 bf16x8;
typedef __attribute__((ext_vector_type(4))) float f32x4;
typedef __attribute__((ext_vector_type(4))) unsigned int uint4v;

#define MFMA16(a, b, c) __builtin_amdgcn_mfma_f32_16x16x32_bf16(a, b, c, 0, 0, 0)

// 1/sqrt(96) * log2(e): folded into Qb so attn scores are already in log2 domain.
#define QSCALE 0.14724450f

__device__ inline bf16x8 cvt8(const float* p) {
    f32x4 lo = *(const f32x4*)p;
    f32x4 hi = *(const f32x4*)(p + 4);
    bf16x8 r;
    r[0] = (bf16)lo[0]; r[1] = (bf16)lo[1]; r[2] = (bf16)lo[2]; r[3] = (bf16)lo[3];
    r[4] = (bf16)hi[0]; r[5] = (bf16)hi[1]; r[6] = (bf16)hi[2]; r[7] = (bf16)hi[3];
    return r;
}

// ---------------- Kernel 0: convert all 8 weight matrices fp32 -> bf16 ----------------
// Wb slot order: 0 W_t_cls, 1 W_d_cls, 2 W_v_cls, 3 W_tgl_q, 4 W_tgl_k, 5 W_tgl_v,
//                6 W_t_tok, 7 W_v_patch

struct WPtrs { const float* W[8]; };

__global__ __launch_bounds__(256) void cvtw_kernel(WPtrs wp, bf16* __restrict__ Wb) {
    int j   = blockIdx.x / 48;
    int blk = blockIdx.x - j * 48;
    int idx = (blk * 256 + threadIdx.x) * 4;
    f32x4 v = *(const f32x4*)(wp.W[j] + idx);
    bf16* dst = Wb + j * 49152 + idx;
    dst[0] = (bf16)v[0]; dst[1] = (bf16)v[1]; dst[2] = (bf16)v[2]; dst[3] = (bf16)v[3];
}

// ---------------- Kernel 1: projections ----------------
// Block = 128 threads = 2 waves; 32 rows x 96 cols (wave nh: cols [nh*48, nh*48+48)).
// Jobs by block: [0,2) t_cls, [2,4) d_cls, [4,6) v_cls, [6,262) Q (scaled by QSCALE),
// [262,518) fused K+V+t_tok (one A-load feeds 3 weight matrices), [518,910) v_patch.
// launch_bounds(128,3): 170-VGPR cap so unroll-4 load batches stay in flight
// (the R4 (128,8) bound squeezed to 28 VGPRs and serialized all loads).

struct ProjParams {
    const float* z_t_cls; const float* z_d_cls; const float* z_v_cls;
    const float* Z_d_tok; const float* Z_t_tok; const float* Z_v_patch;
    const float* b_t; const float* b_d; const float* b_v;
    const float* b_q; const float* b_k; const float* b_vv; const float* b_tt; const float* b_vp;
    float *t, *d, *v;
    bf16 *Qb, *Kb, *Vb, *Tt, *Vp;
    const bf16* Wb;
};

__global__ __launch_bounds__(128, 3) void proj_kernel(ProjParams p) {
    int g   = blockIdx.x;
    int tid = threadIdx.x;
    int nh = tid >> 6, lane = tid & 63;
    int m = lane & 15, quad = lane >> 4;

    int job, base;
    if (g < 2)        { job = 0; base = 0; }
    else if (g < 4)   { job = 1; base = 2; }
    else if (g < 6)   { job = 2; base = 4; }
    else if (g < 262) { job = 3; base = 6; }
    else if (g < 518) { job = 4; base = 262; }
    else              { job = 5; base = 518; }
    int r0 = (g - base) << 5;

    const float* X = (job == 0) ? p.z_t_cls : (job == 1) ? p.z_d_cls : (job == 2) ? p.z_v_cls
                   : (job == 3) ? p.Z_d_tok : (job == 4) ? p.Z_t_tok : p.Z_v_patch;
    const float* x0 = X + (size_t)(r0 + m) * 512 + quad * 8;
    const float* x1 = x0 + 16 * 512;

    __shared__ float sx[2][2][16];   // [nh][t2][quad*4+r] cross-half norm exchange

    if (job != 4) {
        int jw = (job < 4) ? job : 7;
        const bf16* wb = p.Wb + jw * 49152 + (size_t)(nh * 48 + m) * 512 + quad * 8;
        f32x4 acc[2][3] = {};
        #pragma unroll 4
        for (int kk = 0; kk < 512; kk += 32) {
            bf16x8 a0 = cvt8(x0 + kk);
            bf16x8 a1 = cvt8(x1 + kk);
            #pragma unroll
            for (int nt = 0; nt < 3; nt++) {
                bf16x8 b = *(const bf16x8*)(wb + nt * 8192 + kk);
                acc[0][nt] = MFMA16(a0, b, acc[0][nt]);
                acc[1][nt] = MFMA16(a1, b, acc[1][nt]);
            }
        }
        const float* Bv = (job == 0) ? p.b_t : (job == 1) ? p.b_d : (job == 2) ? p.b_v
                        : (job == 3) ? p.b_q : p.b_vp;
        #pragma unroll
        for (int t2 = 0; t2 < 2; t2++)
            #pragma unroll
            for (int nt = 0; nt < 3; nt++) {
                float bb = Bv[nh * 48 + nt * 16 + m];
                acc[t2][nt][0] += bb; acc[t2][nt][1] += bb;
                acc[t2][nt][2] += bb; acc[t2][nt][3] += bb;
            }
        bool norm = (job != 3);
        if (norm) {
            float ss[2][4];
            #pragma unroll
            for (int t2 = 0; t2 < 2; t2++)
                #pragma unroll
                for (int r = 0; r < 4; r++) {
                    float s = 0.0f;
                    #pragma unroll
                    for (int nt = 0; nt < 3; nt++) s += acc[t2][nt][r] * acc[t2][nt][r];
                    s += __shfl_xor(s, 1); s += __shfl_xor(s, 2);
                    s += __shfl_xor(s, 4); s += __shfl_xor(s, 8);
                    ss[t2][r] = s;
                }
            if (m == 0)
                #pragma unroll
                for (int t2 = 0; t2 < 2; t2++)
                    #pragma unroll
                    for (int r = 0; r < 4; r++) sx[nh][t2][quad * 4 + r] = ss[t2][r];
            __syncthreads();
            #pragma unroll
            for (int t2 = 0; t2 < 2; t2++)
                #pragma unroll
                for (int r = 0; r < 4; r++) {
                    float inv = 1.0f / fmaxf(sqrtf(ss[t2][r] + sx[1 - nh][t2][quad * 4 + r]), 1e-6f);
                    #pragma unroll
                    for (int nt = 0; nt < 3; nt++) acc[t2][nt][r] *= inv;
                }
        } else {
            // Q: fold softmax scale (log2-domain) into the projection output.
            #pragma unroll
            for (int t2 = 0; t2 < 2; t2++)
                #pragma unroll
                for (int nt = 0; nt < 3; nt++) {
                    acc[t2][nt][0] *= QSCALE; acc[t2][nt][1] *= QSCALE;
                    acc[t2][nt][2] *= QSCALE; acc[t2][nt][3] *= QSCALE;
                }
        }
        if (job < 3) {
            float* dst = (job == 0) ? p.t : (job == 1) ? p.d : p.v;
            #pragma unroll
            for (int t2 = 0; t2 < 2; t2++)
                #pragma unroll
                for (int r = 0; r < 4; r++)
                    #pragma unroll
                    for (int nt = 0; nt < 3; nt++)
                        dst[(size_t)(r0 + t2 * 16 + quad * 4 + r) * 96 + nh * 48 + nt * 16 + m] = acc[t2][nt][r];
        } else {
            bf16* dst = (job == 3) ? p.Qb : p.Vp;
            #pragma unroll
            for (int t2 = 0; t2 < 2; t2++)
                #pragma unroll
                for (int r = 0; r < 4; r++)
                    #pragma unroll
                    for (int nt = 0; nt < 3; nt++)
                        dst[(size_t)(r0 + t2 * 16 + quad * 4 + r) * 96 + nh * 48 + nt * 16 + m] = (bf16)acc[t2][nt][r];
        }
    } else {
        // Fused K / V / t_tok from one pass over Z_t_tok.
        const bf16* wK = p.Wb + 4 * 49152 + (size_t)(nh * 48 + m) * 512 + quad * 8;
        f32x4 acc[2][3][3] = {};   // [t2][wsel: 0=K 1=V 2=t_tok][nt]
        #pragma unroll 2
        for (int kk = 0; kk < 512; kk += 32) {
            bf16x8 a0 = cvt8(x0 + kk);
            bf16x8 a1 = cvt8(x1 + kk);
            #pragma unroll
            for (int ws = 0; ws < 3; ws++)
                #pragma unroll
                for (int nt = 0; nt < 3; nt++) {
                    bf16x8 b = *(const bf16x8*)(wK + ws * 49152 + nt * 8192 + kk);
                    acc[0][ws][nt] = MFMA16(a0, b, acc[0][ws][nt]);
                    acc[1][ws][nt] = MFMA16(a1, b, acc[1][ws][nt]);
                }
        }
        #pragma unroll
        for (int t2 = 0; t2 < 2; t2++)
            #pragma unroll
            for (int nt = 0; nt < 3; nt++) {
                int col = nh * 48 + nt * 16 + m;
                float bk = p.b_k[col], bv = p.b_vv[col], bt = p.b_tt[col];
                #pragma unroll
                for (int r = 0; r < 4; r++) {
                    acc[t2][0][nt][r] += bk;
                    acc[t2][1][nt][r] += bv;
                    acc[t2][2][nt][r] += bt;
                }
            }
        // l2norm only for t_tok (wsel 2)
        float ss[2][4];
        #pragma unroll
        for (int t2 = 0; t2 < 2; t2++)
            #pragma unroll
            for (int r = 0; r < 4; r++) {
                float s = 0.0f;
                #pragma unroll
                for (int nt = 0; nt < 3; nt++) s += acc[t2][2][nt][r] * acc[t2][2][nt][r];
                s += __shfl_xor(s, 1); s += __shfl_xor(s, 2);
                s += __shfl_xor(s, 4); s += __shfl_xor(s, 8);
                ss[t2][r] = s;
            }
        if (m == 0)
            #pragma unroll
            for (int t2 = 0; t2 < 2; t2++)
                #pragma unroll
                for (int r = 0; r < 4; r++) sx[nh][t2][quad * 4 + r] = ss[t2][r];
        __syncthreads();
        #pragma unroll
        for (int t2 = 0; t2 < 2; t2++)
            #pragma unroll
            for (int r = 0; r < 4; r++) {
                float inv = 1.0f / fmaxf(sqrtf(ss[t2][r] + sx[1 - nh][t2][quad * 4 + r]), 1e-6f);
                #pragma unroll
                for (int nt = 0; nt < 3; nt++) acc[t2][2][nt][r] *= inv;
            }
        #pragma unroll
        for (int t2 = 0; t2 < 2; t2++)
            #pragma unroll
            for (int r = 0; r < 4; r++)
                #pragma unroll
                for (int nt = 0; nt < 3; nt++) {
                    size_t o = (size_t)(r0 + t2 * 16 + quad * 4 + r) * 96 + nh * 48 + nt * 16 + m;
                    p.Kb[o] = (bf16)acc[t2][0][nt][r];
                    p.Vb[o] = (bf16)acc[t2][1][nt][r];
                    p.Tt[o] = (bf16)acc[t2][2][nt][r];
                }
    }
}

// ---------------- Kernel 2: fused attn + cll, role-interleaved ----------------
// blockIdx even -> attn on pair p=blockIdx>>1; odd -> cll on same pair.
// Adjacent blocks land on different CUs/XCDs -> VALU-heavy attn overlaps
// MFMA-heavy cll on each CU (separate pipes co-schedule).
// attn: scores already log2-scaled (QSCALE folded into Qb); softmax without
// max-subtraction (|s|<~3 => exp2 safe; softmax is shift-invariant).

union AcSmem {
    struct { bf16 K[128 * 104]; float wsum4[4][128]; float wk[128]; float ctxp[4][96]; float ctx[96]; } a;
    struct { bf16 P[196 * 104]; float red[4]; } c;
};

__global__ __launch_bounds__(256, 3) void ac_kernel(
    const bf16* __restrict__ Qg, const bf16* __restrict__ Kg, const bf16* __restrict__ Vg,
    const bf16* __restrict__ Tt, const bf16* __restrict__ Vp,
    const float* __restrict__ dvec, const float* __restrict__ ln_g, const float* __restrict__ ln_b,
    float* __restrict__ S_TGL, float* __restrict__ S_CLL)
{
    __shared__ __align__(16) AcSmem sm;
    int p   = blockIdx.x >> 1;
    int role = blockIdx.x & 1;
    int b = p >> 6, c = p & 63;
    int tid = threadIdx.x, lane = tid & 63, w = tid >> 6;
    int m = lane & 15, quad = lane >> 4;

    if (role == 0) {
        // ---------------- attn ----------------
        const bf16* Q = Qg + (size_t)b * (128 * 96);
        const bf16* K = Kg + (size_t)c * (128 * 96);
        const bf16* V = Vg + (size_t)c * (128 * 96);
        #pragma unroll
        for (int it = 0; it < 6; it++) {
            int ch = it * 256 + tid;
            int row = ch / 12, seg = ch - row * 12;
            *(uint4v*)(sm.a.K + row * 104 + seg * 8) = *(const uint4v*)(K + ch * 8);
        }
        __syncthreads();

        f32x4 acc[2][8] = {};
        #pragma unroll
        for (int kk = 0; kk < 96; kk += 32) {
            bf16x8 a0 = *(const bf16x8*)(Q + (size_t)(w * 32 + m) * 96 + kk + quad * 8);
            bf16x8 a1 = *(const bf16x8*)(Q + (size_t)(w * 32 + 16 + m) * 96 + kk + quad * 8);
            #pragma unroll
            for (int nt = 0; nt < 8; nt++) {
                bf16x8 bb = *(const bf16x8*)(sm.a.K + (nt * 16 + m) * 104 + kk + quad * 8);
                acc[0][nt] = MFMA16(a0, bb, acc[0][nt]);
                acc[1][nt] = MFMA16(a1, bb, acc[1][nt]);
            }
        }
        float wpart[8];
        #pragma unroll
        for (int nt = 0; nt < 8; nt++) wpart[nt] = 0.0f;
        #pragma unroll
        for (int mt = 0; mt < 2; mt++) {
            #pragma unroll
            for (int r = 0; r < 4; r++) {
                float tv[8]; float s = 0.0f;
                #pragma unroll
                for (int nt = 0; nt < 8; nt++) { tv[nt] = exp2f(acc[mt][nt][r]); s += tv[nt]; }
                s += __shfl_xor(s, 1); s += __shfl_xor(s, 2);
                s += __shfl_xor(s, 4); s += __shfl_xor(s, 8);
                float inv = 1.0f / s;
                #pragma unroll
                for (int nt = 0; nt < 8; nt++) wpart[nt] += tv[nt] * inv;
            }
        }
        #pragma unroll
        for (int nt = 0; nt < 8; nt++) {
            wpart[nt] += __shfl_xor(wpart[nt], 16);
            wpart[nt] += __shfl_xor(wpart[nt], 32);
        }
        if (lane < 16) {
            #pragma unroll
            for (int nt = 0; nt < 8; nt++) sm.a.wsum4[w][nt * 16 + lane] = wpart[nt];
        }
        __syncthreads();
        if (tid < 128)
            sm.a.wk[tid] = sm.a.wsum4[0][tid] + sm.a.wsum4[1][tid] + sm.a.wsum4[2][tid] + sm.a.wsum4[3][tid];
        __syncthreads();
        {
            float c0 = 0.0f, c1 = 0.0f;
            if (lane < 48) {
                #pragma unroll 4
                for (int r = 0; r < 32; r++) {
                    int k = w * 32 + r;
                    unsigned u = *(const unsigned*)(V + (size_t)k * 96 + lane * 2);
                    float lo = __uint_as_float(u << 16);
                    float hi = __uint_as_float(u & 0xffff0000u);
                    float wkk = sm.a.wk[k];
                    c0 += wkk * lo; c1 += wkk * hi;
                }
                sm.a.ctxp[w][lane * 2]     = c0;
                sm.a.ctxp[w][lane * 2 + 1] = c1;
            }
        }
        __syncthreads();
        if (tid < 96)
            sm.a.ctx[tid] = (sm.a.ctxp[0][tid] + sm.a.ctxp[1][tid] + sm.a.ctxp[2][tid] + sm.a.ctxp[3][tid]) * (1.0f / 128.0f);
        __syncthreads();
        if (w == 0) {
            float x0 = sm.a.ctx[lane];
            float x1 = (lane < 32) ? sm.a.ctx[64 + lane] : 0.0f;
            float s = x0 + x1;
            #pragma unroll
            for (int d = 1; d < 64; d <<= 1) s += __shfl_xor(s, d);
            float mean = s * (1.0f / 96.0f);
            float e0 = x0 - mean;
            float e1 = (lane < 32) ? (x1 - mean) : 0.0f;
            float q = e0 * e0 + e1 * e1;
            #pragma unroll
            for (int d = 1; d < 64; d <<= 1) q += __shfl_xor(q, d);
            float rstd = rsqrtf(q * (1.0f / 96.0f) + 1e-5f);
            float y0 = e0 * rstd * ln_g[lane] + ln_b[lane];
            float y1 = 0.0f;
            if (lane < 32) y1 = e1 * rstd * ln_g[64 + lane] + ln_b[64 + lane];
            const float* db = dvec + b * 96;
            float dot = y0 * db[lane] + ((lane < 32) ? y1 * db[64 + lane] : 0.0f);
            float ssq = y0 * y0 + y1 * y1;
            #pragma unroll
            for (int d = 1; d < 64; d <<= 1) { dot += __shfl_xor(dot, d); ssq += __shfl_xor(ssq, d); }
            if (lane == 0) S_TGL[p] = dot / fmaxf(sqrtf(ssq), 1e-6f);
        }
    } else {
        // ---------------- cll ----------------
        const bf16* T = Tt + (size_t)b * (128 * 96);
        const bf16* P = Vp + (size_t)c * (196 * 96);
        for (int ch = tid; ch < 2352; ch += 256) {
            int row = ch / 12, seg = ch - row * 12;
            *(uint4v*)(sm.c.P + row * 104 + seg * 8) = *(const uint4v*)(P + ch * 8);
        }
        __syncthreads();

        int rofs[13];
        #pragma unroll
        for (int nt = 0; nt < 13; nt++) {
            int r = nt * 16 + m; if (r > 195) r = 195;
            rofs[nt] = r * 104;
        }
        f32x4 acc[2][13] = {};
        #pragma unroll
        for (int kk = 0; kk < 96; kk += 32) {
            bf16x8 a0 = *(const bf16x8*)(T + (size_t)(w * 32 + m) * 96 + kk + quad * 8);
            bf16x8 a1 = *(const bf16x8*)(T + (size_t)(w * 32 + 16 + m) * 96 + kk + quad * 8);
            #pragma unroll
            for (int nt = 0; nt < 13; nt++) {
                bf16x8 bb = *(const bf16x8*)(sm.c.P + rofs[nt] + kk + quad * 8);
                acc[0][nt] = MFMA16(a0, bb, acc[0][nt]);
                acc[1][nt] = MFMA16(a1, bb, acc[1][nt]);
            }
        }
        float mx = -3.4e38f;
        #pragma unroll
        for (int mt = 0; mt < 2; mt++)
            #pragma unroll
            for (int nt = 0; nt < 13; nt++)
                #pragma unroll
                for (int r = 0; r < 4; r++) mx = fmaxf(mx, acc[mt][nt][r]);
        #pragma unroll
        for (int d = 1; d < 64; d <<= 1) mx = fmaxf(mx, __shfl_xor(mx, d));
        if (lane == 0) sm.c.red[w] = mx;
        __syncthreads();
        if (tid == 0) S_CLL[p] = fmaxf(fmaxf(sm.c.red[0], sm.c.red[1]), fmaxf(sm.c.red[2], sm.c.red[3]));
    }
}

// ---------------- Kernel 3: final combine ----------------

__global__ __launch_bounds__(64) void final_kernel(
    const float* __restrict__ t, const float* __restrict__ d, const float* __restrict__ v,
    const float* __restrict__ S_TGL, const float* __restrict__ S_CLL, float* __restrict__ out)
{
    int i = blockIdx.x, j = threadIdx.x;
    __shared__ float ti[96];
    if (j < 64) ti[j] = t[i * 96 + j];
    if (j < 32) ti[64 + j] = t[i * 96 + 64 + j];
    __syncthreads();
    float tg = 0.0f, cg = 0.0f;
    const float* dj = d + j * 96;
    const float* vj = v + j * 96;
    #pragma unroll 8
    for (int h = 0; h < 96; h++) { float th = ti[h]; tg += th * dj[h]; cg += th * vj[h]; }
    float res = 0.5f * (tg + S_TGL[i * 64 + j]) + 0.5f * (cg + S_CLL[i * 64 + j]);
    out[i * 64 + j] = res;
}

// ---------------- launch ----------------

extern "C" void kernel_launch(void* const* d_in, const int* in_sizes, int n_in,
                              void* d_out, int out_size, void* d_ws, size_t ws_size,
                              hipStream_t stream)
{
    (void)in_sizes; (void)n_in; (void)out_size; (void)ws_size;
    char* ws = (char*)d_ws;
    float* t     = (float*)(ws + 0);               // 64*96 f32
    float* d     = (float*)(ws + 24576);
    float* v     = (float*)(ws + 49152);
    float* S_TGL = (float*)(ws + 73728);           // 4096 f32
    float* S_CLL = (float*)(ws + 90112);
    bf16* Wb = (bf16*)(ws + 106496);               // 8*96*512 bf16 = 786432 B
    bf16* Qb = (bf16*)(ws + 892928);               // 8192*96 bf16 = 1572864 B
    bf16* Kb = (bf16*)(ws + 892928 + 1572864);
    bf16* Vb = (bf16*)(ws + 892928 + 2 * 1572864);
    bf16* Tt = (bf16*)(ws + 892928 + 3 * 1572864);
    bf16* Vp = (bf16*)(ws + 892928 + 4 * 1572864); // 12544*96 bf16 = 2408448 B

    WPtrs wp;
    wp.W[0] = (const float*)d_in[6];   // W_t_cls
    wp.W[1] = (const float*)d_in[8];   // W_d_cls
    wp.W[2] = (const float*)d_in[10];  // W_v_cls
    wp.W[3] = (const float*)d_in[16];  // W_tgl_q
    wp.W[4] = (const float*)d_in[18];  // W_tgl_k
    wp.W[5] = (const float*)d_in[20];  // W_tgl_v
    wp.W[6] = (const float*)d_in[12];  // W_t_tok
    wp.W[7] = (const float*)d_in[14];  // W_v_patch
    hipLaunchKernelGGL(cvtw_kernel, dim3(384), dim3(256), 0, stream, wp, Wb);

    ProjParams pp;
    pp.z_t_cls = (const float*)d_in[2];
    pp.z_d_cls = (const float*)d_in[0];
    pp.z_v_cls = (const float*)d_in[4];
    pp.Z_d_tok = (const float*)d_in[1];
    pp.Z_t_tok = (const float*)d_in[3];
    pp.Z_v_patch = (const float*)d_in[5];
    pp.b_t  = (const float*)d_in[7];
    pp.b_d  = (const float*)d_in[9];
    pp.b_v  = (const float*)d_in[11];
    pp.b_q  = (const float*)d_in[17];
    pp.b_k  = (const float*)d_in[19];
    pp.b_vv = (const float*)d_in[21];
    pp.b_tt = (const float*)d_in[13];
    pp.b_vp = (const float*)d_in[15];
    pp.t = t; pp.d = d; pp.v = v;
    pp.Qb = Qb; pp.Kb = Kb; pp.Vb = Vb; pp.Tt = Tt; pp.Vp = Vp;
    pp.Wb = Wb;
    hipLaunchKernelGGL(proj_kernel, dim3(910), dim3(128), 0, stream, pp);

    hipLaunchKernelGGL(ac_kernel, dim3(8192), dim3(256), 0, stream,
                       (const bf16*)Qb, (const bf16*)Kb, (const bf16*)Vb,
                       (const bf16*)Tt, (const bf16*)Vp,
                       (const float*)d, (const float*)d_in[22], (const float*)d_in[23],
                       S_TGL, S_CLL);
    hipLaunchKernelGGL(final_kernel, dim3(64), dim3(64), 0, stream,
                       (const float*)t, (const float*)d, (const float*)v,
                       (const float*)S_TGL, (const float*)S_CLL, (float*)d_out);
}